// Round 4
// baseline (210.399 us; speedup 1.0000x reference)
//
#include <hip/hip_runtime.h>
#include <hip/hip_bf16.h>
#include <math.h>

#define B_  2
#define S_  2048
#define D_  1024
#define H_  16
#define DK_ 64

typedef __attribute__((ext_vector_type(8))) short bf16x8;   // 8 bf16 = 4 VGPRs
typedef __attribute__((ext_vector_type(4))) float f32x4;
typedef __attribute__((ext_vector_type(4))) unsigned int u32x4;

#define MFMA_BF16(a, b, c) __builtin_amdgcn_mfma_f32_16x16x32_bf16((a), (b), (c), 0, 0, 0)

// 0.125 (1/sqrt(DK)) * log2(e): folded into Q so P = v_exp(S^T) directly
#define QSCALE 0.18033688011112042f
// log2(500000)/32 for RoPE inv_freq = 2^(-j * this)
#define ROPE_L2 0.591611512f

// fp32 -> bf16 round-to-nearest-even
__device__ __forceinline__ unsigned short f2bf(float f) {
  unsigned int u = __float_as_uint(f);
  u += 0x7FFFu + ((u >> 16) & 1u);
  return (unsigned short)(u >> 16);
}

// async global->LDS, 16 B per lane; LDS dest = wave-uniform base + lane*16
__device__ __forceinline__ void gl_lds16(const void* g, void* l) {
  __builtin_amdgcn_global_load_lds(
      (const __attribute__((address_space(1))) void*)g,
      (__attribute__((address_space(3))) void*)l, 16, 0, 0);
}

// XOR-swizzled LDS index (ushort units). Rows are 64 ushorts = 128 B = 8
// 16B-chunks; chunk ^= row&7 makes both gl_lds16 staging (identity per-lane
// slots, source pre-swizzled) and column-slice fragment reads conflict-free.
__device__ __forceinline__ int lsw(int row, int col) {
  return row * 64 + ((((col) >> 3) ^ (row & 7)) << 3) + (col & 7);
}

// sigma-inverse for the V^T column permutation (6-bit in-tile s index).
// sigma pairs PV A-fragment slot s_r = ks*32 + quad*8 + j with the QK^T
// accumulator register (kvi = 2ks + (j>>2), r = j&3) of the SAME lane:
//   sigma(s_r) = kvi*16 + quad*4 + r  -> bit map y = (x5, x2, x4, x3, x1, x0)
// inverse:  x = (y5, y3, y2, y4, y1, y0).  Low 2 bits identity -> 4-wide
// uint2 stores in the V^T writer stay contiguous.
__device__ __forceinline__ int vperm_inv(int c) {   // c multiple of 4
  return (c & 32) | ((c & 8) << 1) | ((c & 4) << 1) | ((c & 16) >> 2);
}

// ---------------------------------------------------------------------------
// fp32 -> bf16 conversion for q,k,v and the four weight matrices.
// ---------------------------------------------------------------------------
__global__ __launch_bounds__(256)
void cvt_bf16(const float* __restrict__ q, const float* __restrict__ k,
              const float* __restrict__ v, const float* __restrict__ wq,
              const float* __restrict__ wk, const float* __restrict__ wv,
              const float* __restrict__ wo,
              unsigned short* __restrict__ qb, unsigned short* __restrict__ kb,
              unsigned short* __restrict__ vb, unsigned short* __restrict__ wqb,
              unsigned short* __restrict__ wkb, unsigned short* __restrict__ wvb,
              unsigned short* __restrict__ wob) {
  const float* src; unsigned short* dst; int n;
  switch (blockIdx.y) {
    case 0: src = q;  dst = qb;  n = B_ * S_ * D_; break;
    case 1: src = k;  dst = kb;  n = B_ * S_ * D_; break;
    case 2: src = v;  dst = vb;  n = B_ * S_ * D_; break;
    case 3: src = wq; dst = wqb; n = D_ * D_; break;
    case 4: src = wk; dst = wkb; n = D_ * D_; break;
    case 5: src = wv; dst = wvb; n = D_ * D_; break;
    default: src = wo; dst = wob; n = D_ * D_; break;
  }
  const int i = (blockIdx.x * 256 + threadIdx.x) * 4;
  if (i >= n) return;
  float4 val = *(const float4*)&src[i];
  ushort4 r4;
  r4.x = f2bf(val.x); r4.y = f2bf(val.y); r4.z = f2bf(val.z); r4.w = f2bf(val.w);
  *(ushort4*)&dst[i] = r4;
}

// ---------------------------------------------------------------------------
// Fused QKV projection GEMM, 8-PHASE 256^2 SCHEDULE (T3+T4+T2+T5).
// 256x256 tile, BK=64, 512 threads = 8 waves (2M x 4N), wave tile 128x64
// (wave owns exactly ONE head -> epilogues stay wave-local, identical math
// to the verified 128^2 version).  LDS 128 KiB: per matrix 2 dbuf x 2 half
// x [128][64] ushorts, XOR-swizzled reads (lsw), linear gl_lds16 staging
// with pre-swizzled global source.
//
// Wave m-frags: mf in [0,8): rows mf*32 + wm*16 + [0,16); mf 0-3 = A-half0,
// mf 4-7 = A-half1.  Phase q in [0,4) computes mf {2q, 2q+1} x all 4 nf x
// 2 ks = 16 MFMA; B-frags (8) ds-read once at q0 and held in registers.
//
// Staging schedule (induction-verified): during tile t's phases,
//   q0: stage B(t+1,h0) + A(t+1,h1)   [dest buf^1, freed end of t-1]
//   q1: stage B(t+1,h1)               [dest buf^1]
//   q2: stage A(t+2,h0)               [dest buf: A-half0 freed after q1]
// In-flight at each tile boundary = 10 loads; s_waitcnt vmcnt(2) completes
// the oldest 8 = ALL of tile t+1 (leaves A(t+2,h0) in flight -> never
// drains to 0 until the tail).  Raw s_barrier only (NO __syncthreads: it
// would emit vmcnt(0)).  Per phase: {ds_reads + stage issue} barrier
// lgkmcnt(0) sched_barrier(0) setprio(1) 16xMFMA setprio(0) barrier.
// Epilogues (z=0: RMSNorm+RoPE+QSCALE; z=1: RMSNorm+RoPE; z=2: V^T sigma)
// unchanged except the row formula (mf*32 + wm*16 + quad*4 + r).
// XCD swizzle: nwg = 192 = 8*24, bijective chunked remap.
// ---------------------------------------------------------------------------
__global__ __launch_bounds__(512, 2)
void gemm_qkv(const unsigned short* __restrict__ qa, const unsigned short* __restrict__ ka,
              const unsigned short* __restrict__ va,
              const unsigned short* __restrict__ wq, const unsigned short* __restrict__ wk,
              const unsigned short* __restrict__ wv,
              unsigned short* __restrict__ Qo, unsigned short* __restrict__ Ko,
              unsigned short* __restrict__ Vto,
              const float* __restrict__ qnw, const float* __restrict__ knw) {
  __shared__ unsigned short As[2][16384];   // [buf][half*8192 + r*64 + chunk*8]
  __shared__ unsigned short Bs[2][16384];

  // XCD swizzle: lin in dispatch order; XCD = lin % 8; 192 = 8 * 24.
  const int lin = blockIdx.x + (blockIdx.y << 2) + (blockIdx.z << 6);  // [0,192)
  const int v_  = (lin & 7) * 24 + (lin >> 3);                          // bijective
  const int bxn = v_ & 3;            // n-tile (256 cols)
  const int r2  = v_ >> 2;           // [0,48)
  const int by  = r2 & 15;           // m-tile (256 rows)
  const int z   = r2 >> 4;           // q/k/v select

  const unsigned short* A = (z == 0) ? qa : (z == 1) ? ka : va;
  const unsigned short* W = (z == 0) ? wq : (z == 1) ? wk : wv;

  const int tid = threadIdx.x, lane = tid & 63, wave = tid >> 6;
  const int l16 = lane & 15, quad = lane >> 4;
  const int wm = wave >> 2, wn2 = wave & 3;    // 2M x 4N waves
  const int m0 = by * 256, j0 = bxn * 256;

  f32x4 acc[8][4];
#pragma unroll
  for (int i = 0; i < 8; ++i)
#pragma unroll
    for (int j = 0; j < 4; ++j) acc[i][j] = (f32x4)(0.0f);

  // stage one 128x64 half-tile (16 KB): 2 x gl_lds16 per thread.
  // LDS dest linear in c = j*512 + tid; global source column pre-swizzled.
  auto stageA = [&](int tile, int h) {
    const int kb = tile * 64, R0 = m0 + h * 128;
#pragma unroll
    for (int j = 0; j < 2; ++j) {
      const int c = j * 512 + tid;
      const int r = c >> 3;
      const int co = (((c & 7) ^ (r & 7)) << 3);
      gl_lds16(&A[(size_t)(R0 + r) * D_ + kb + co],
               &As[tile & 1][h * 8192 + ((c & ~63) << 3)]);
    }
  };
  auto stageB = [&](int tile, int h) {
    const int kb = tile * 64, R0 = j0 + h * 128;
#pragma unroll
    for (int j = 0; j < 2; ++j) {
      const int c = j * 512 + tid;
      const int r = c >> 3;
      const int co = (((c & 7) ^ (r & 7)) << 3);
      gl_lds16(&W[(size_t)(R0 + r) * D_ + kb + co],
               &Bs[tile & 1][h * 8192 + ((c & ~63) << 3)]);
    }
  };

#define PHASE(BUF, QH, MFA, MFB, STAGES)                                        \
  do {                                                                          \
    bf16x8 af0[2], af1[2];                                                      \
    _Pragma("unroll")                                                           \
    for (int ks = 0; ks < 2; ++ks) {                                            \
      af0[ks] = *(const bf16x8*)&As[BUF][(QH) * 8192 +                          \
                    lsw(((MFA) & 3) * 32 + wm * 16 + l16, ks * 32 + quad * 8)]; \
      af1[ks] = *(const bf16x8*)&As[BUF][(QH) * 8192 +                          \
                    lsw(((MFB) & 3) * 32 + wm * 16 + l16, ks * 32 + quad * 8)]; \
    }                                                                           \
    STAGES;                                                                     \
    __builtin_amdgcn_s_barrier();                                               \
    asm volatile("s_waitcnt lgkmcnt(0)" ::: "memory");                          \
    __builtin_amdgcn_sched_barrier(0);                                          \
    __builtin_amdgcn_s_setprio(1);                                              \
    _Pragma("unroll")                                                           \
    for (int ks = 0; ks < 2; ++ks) {                                            \
      _Pragma("unroll")                                                         \
      for (int nf = 0; nf < 4; ++nf) {                                          \
        acc[MFA][nf] = MFMA_BF16(af0[ks], bfr[nf][ks], acc[MFA][nf]);           \
        acc[MFB][nf] = MFMA_BF16(af1[ks], bfr[nf][ks], acc[MFB][nf]);           \
      }                                                                         \
    }                                                                           \
    __builtin_amdgcn_s_setprio(0);                                              \
  } while (0)

  const int NT = D_ / 64;   // 16 K-tiles
  // prologue: tile0 fully + A(1,h0); 10 loads in flight -> vmcnt(2) -> barrier
  stageA(0, 0); stageA(0, 1); stageB(0, 0); stageB(0, 1); stageA(1, 0);
  asm volatile("s_waitcnt vmcnt(2)" ::: "memory");
  __builtin_amdgcn_s_barrier();

  for (int tt = 0; tt < NT; ++tt) {
    const int buf = tt & 1;
    // B-frags for this tile: 8 x ds_read_b128, held in regs across phases
    bf16x8 bfr[4][2];
#pragma unroll
    for (int nf = 0; nf < 4; ++nf)
#pragma unroll
      for (int ks = 0; ks < 2; ++ks)
        bfr[nf][ks] = *(const bf16x8*)&Bs[buf][(wn2 >> 1) * 8192 +
            lsw((wn2 & 1) * 64 + nf * 16 + l16, ks * 32 + quad * 8)];

    PHASE(buf, 0, 0, 1,
          if (tt + 1 < NT) { stageB(tt + 1, 0); stageA(tt + 1, 1); });
    __builtin_amdgcn_s_barrier();
    PHASE(buf, 0, 2, 3,
          if (tt + 1 < NT) { stageB(tt + 1, 1); });
    __builtin_amdgcn_s_barrier();
    PHASE(buf, 1, 4, 5,
          if (tt + 2 < NT) { stageA(tt + 2, 0); });
    __builtin_amdgcn_s_barrier();
    PHASE(buf, 1, 6, 7, );
    // tile boundary: complete all of tile tt+1 (oldest 8 of 10 in flight);
    // leave A(tt+2,h0) in flight.  Tail tiles drain.
    if (tt <= NT - 3) {
      asm volatile("s_waitcnt vmcnt(2)" ::: "memory");
    } else {
      asm volatile("s_waitcnt vmcnt(0)" ::: "memory");
    }
    __builtin_amdgcn_s_barrier();
  }
#undef PHASE

  // epilogue. C/D layout: col = l16 (n), row = quad*4 + reg (m).
  // row(mf) = m0 + mf*32 + wm*16 + quad*4 + r ; head h = bxn*4 + wn2.
  const int h = bxn * 4 + wn2;
  if (z == 2) {
    // V^T: [b][h][dk][s'], packed 4-bf16 (8B) stores along s (sigma cols)
#pragma unroll
    for (int mf = 0; mf < 8; ++mf) {
      const int rowb = m0 + mf * 32 + wm * 16 + quad * 4;
      const int b = rowb >> 11, s0 = rowb & (S_ - 1);
      const int sp = (s0 & ~63) | vperm_inv(s0 & 63);
#pragma unroll
      for (int nf = 0; nf < 4; ++nf) {
        const int dk = nf * 16 + l16;
        const unsigned int u0 =
            (unsigned int)f2bf(acc[mf][nf][0]) | ((unsigned int)f2bf(acc[mf][nf][1]) << 16);
        const unsigned int u1 =
            (unsigned int)f2bf(acc[mf][nf][2]) | ((unsigned int)f2bf(acc[mf][nf][3]) << 16);
        *(uint2*)&Vto[((size_t)((b * H_ + h) * DK_ + dk)) * S_ + sp] = make_uint2(u0, u1);
      }
    }
  } else {
    unsigned short* out = (z == 0) ? Qo : Ko;
    const float* nw = (z == 0) ? qnw : knw;
    const float sc  = (z == 0) ? QSCALE : 1.0f;
    float wv_[4];
#pragma unroll
    for (int nf = 0; nf < 4; ++nf) wv_[nf] = nw[nf * 16 + l16];
    const float invA = exp2f(-(float)l16 * ROPE_L2);         // j = l16
    const float invB = exp2f(-(float)(16 + l16) * ROPE_L2);  // j = 16 + l16
#pragma unroll
    for (int mf = 0; mf < 8; ++mf) {
#pragma unroll
      for (int r = 0; r < 4; ++r) {
        const int rowg = m0 + mf * 32 + wm * 16 + quad * 4 + r;
        const int b = rowg >> 11, s = rowg & (S_ - 1);
        float ss = 0.f;
#pragma unroll
        for (int nf = 0; nf < 4; ++nf) ss += acc[mf][nf][r] * acc[mf][nf][r];
#pragma unroll
        for (int m = 1; m < 16; m <<= 1) ss += __shfl_xor(ss, m);
        const float rms = rsqrtf(ss * (1.0f / DK_) + 1e-10f);
        float xn[4];
#pragma unroll
        for (int nf = 0; nf < 4; ++nf) xn[nf] = wv_[nf] * acc[mf][nf][r] * rms;
        const float fA = (float)s * invA, fB = (float)s * invB;
        const float cA = __cosf(fA) * sc, sA = __sinf(fA) * sc;
        const float cB = __cosf(fB) * sc, sB = __sinf(fB) * sc;
        float o0 = xn[0] * cA - xn[2] * sA;   // dk = l16       (<32, j=A)
        float o1 = xn[1] * cB - xn[3] * sB;   // dk = 16+l16    (<32, j=B)
        float o2 = xn[2] * cA + xn[0] * sA;   // dk = 32+l16    (>=32, j=A)
        float o3 = xn[3] * cB + xn[1] * sB;   // dk = 48+l16    (>=32, j=B)
        const size_t base = ((size_t)(b * H_ + h) * S_ + s) * DK_;
        out[base +  0 + l16] = f2bf(o0);
        out[base + 16 + l16] = f2bf(o1);
        out[base + 32 + l16] = f2bf(o2);
        out[base + 48 + l16] = f2bf(o3);
      }
    }
  }
}

// ---------------------------------------------------------------------------
// Flash attention v4 (unchanged from verified round 3): 64-row Q-tiles,
// S^T = K Q^T, no-max softmax, l via ones-MFMA, double-buffered gl_lds16,
// XOR-swizzled LDS.  P stays in registers via the sigma pairing (V columns
// pre-permuted by gemm_qkv's V^T writer).
// ---------------------------------------------------------------------------
__global__ __launch_bounds__(256)
void flash3(const unsigned short* __restrict__ Q, const unsigned short* __restrict__ K,
            const unsigned short* __restrict__ Vt, unsigned short* __restrict__ Oa) {
  __shared__ unsigned short Ks[2][64 * 64];
  __shared__ unsigned short Vs[2][64 * 64];
  const int bx = blockIdx.x;
  const int idx = bx >> 5;
  const int qt = (idx < 16) ? idx : (47 - idx);   // balance across co-residents
  const int bh = bx & 31;
  const int t = threadIdx.x, lane = t & 63, wave = t >> 6;
  const int l16 = lane & 15, quad = lane >> 4;
  const size_t hb = (size_t)bh * S_ * DK_;
  const unsigned short* Qh  = Q + hb;
  const unsigned short* Kh  = K + hb;
  const unsigned short* Vth = Vt + hb;      // [dk][s'] (sigma-permuted cols)

  bf16x8 qf[2];
#pragma unroll
  for (int ks = 0; ks < 2; ++ks)
    qf[ks] = *(const bf16x8*)
      &Qh[(size_t)(qt * 64 + wave * 16 + l16) * DK_ + ks * 32 + quad * 8];

  bf16x8 ones;
#pragma unroll
  for (int j = 0; j < 8; ++j) ones[j] = (short)0x3F80;  // bf16 1.0

  f32x4 o[4], lacc;
  lacc = (f32x4)(0.0f);
#pragma unroll
  for (int ni = 0; ni < 4; ++ni) o[ni] = (f32x4)(0.0f);

  auto stage = [&](int kt, int bufi) {
#pragma unroll
    for (int i = 0; i < 2; ++i) {
      const int rbase = wave * 16 + i * 8;
      const int r = rbase + (lane >> 3);
      const int c = ((lane & 7) ^ (r & 7)) * 8;   // logical col (ushorts)
      gl_lds16(&Kh[(size_t)(kt * 64 + r) * DK_ + c], &Ks[bufi][rbase * 64]);
      gl_lds16(&Vth[(size_t)r * S_ + kt * 64 + c], &Vs[bufi][rbase * 64]);
    }
  };

  const int nkt = qt + 1;
  stage(0, 0);
  for (int kt = 0; kt < nkt; ++kt) {
    const int buf = kt & 1;
    __syncthreads();          // drains vmcnt: staged buf ready; buf^1 free
    if (kt + 1 < nkt) stage(kt + 1, buf ^ 1);

    // S^T = K Q^T : A = K-frag (m=kv), B = Q-frag (n=q)
    f32x4 sv[4];
#pragma unroll
    for (int kvi = 0; kvi < 4; ++kvi) sv[kvi] = (f32x4)(0.0f);
#pragma unroll
    for (int ks = 0; ks < 2; ++ks) {
      bf16x8 ak[4];
#pragma unroll
      for (int kvi = 0; kvi < 4; ++kvi)
        ak[kvi] = *(const bf16x8*)&Ks[buf][lsw(kvi * 16 + l16, ks * 32 + quad * 8)];
      __builtin_amdgcn_s_setprio(1);
#pragma unroll
      for (int kvi = 0; kvi < 4; ++kvi)
        sv[kvi] = MFMA_BF16(ak[kvi], qf[ks], sv[kvi]);
      __builtin_amdgcn_s_setprio(0);
    }

    // exp2 (+ mask only on the single diagonal tile; wave-uniform branch),
    // pack pairs (truncate) to bf16 words
    unsigned int pw[4][2];
    if (kt == qt) {
      const int qg = qt * 64 + wave * 16 + l16;
#pragma unroll
      for (int kvi = 0; kvi < 4; ++kvi) {
        float e[4];
#pragma unroll
        for (int r = 0; r < 4; ++r) {
          float x = sv[kvi][r];
          if ((kt * 64 + kvi * 16 + quad * 4 + r) > qg) x = -INFINITY;
          e[r] = exp2f(x);
        }
        pw[kvi][0] = (__float_as_uint(e[1]) & 0xFFFF0000u) | (__float_as_uint(e[0]) >> 16);
        pw[kvi][1] = (__float_as_uint(e[3]) & 0xFFFF0000u) | (__float_as_uint(e[2]) >> 16);
      }
    } else {
#pragma unroll
      for (int kvi = 0; kvi < 4; ++kvi) {
        float e[4];
#pragma unroll
        for (int r = 0; r < 4; ++r) e[r] = exp2f(sv[kvi][r]);
        pw[kvi][0] = (__float_as_uint(e[1]) & 0xFFFF0000u) | (__float_as_uint(e[0]) >> 16);
        pw[kvi][1] = (__float_as_uint(e[3]) & 0xFFFF0000u) | (__float_as_uint(e[2]) >> 16);
      }
    }

    // PV A-fragment = direct register pack (sigma pairing, no cross-lane)
    bf16x8 ap[2];
#pragma unroll
    for (int ks = 0; ks < 2; ++ks) {
      u32x4 aw;
      aw.x = pw[2 * ks][0];
      aw.y = pw[2 * ks][1];
      aw.z = pw[2 * ks + 1][0];
      aw.w = pw[2 * ks + 1][1];
      ap[ks] = __builtin_bit_cast(bf16x8, aw);
    }

    // O += P V, l += P 1
#pragma unroll
    for (int ks = 0; ks < 2; ++ks) {
      bf16x8 bv[4];
#pragma unroll
      for (int ni = 0; ni < 4; ++ni)
        bv[ni] = *(const bf16x8*)&Vs[buf][lsw(ni * 16 + l16, ks * 32 + quad * 8)];
      __builtin_amdgcn_s_setprio(1);
#pragma unroll
      for (int ni = 0; ni < 4; ++ni)
        o[ni] = MFMA_BF16(ap[ks], bv[ni], o[ni]);
      lacc = MFMA_BF16(ap[ks], ones, lacc);
      __builtin_amdgcn_s_setprio(0);
    }
  }

  // epilogue: O /= l, write bf16 row-major attn [b*S+s][h*64+dk]
  const int b = bh >> 4, h = bh & 15;
#pragma unroll
  for (int r = 0; r < 4; ++r) {
    const int srow = qt * 64 + wave * 16 + quad * 4 + r;
    const float linv = 1.0f / lacc[r];
#pragma unroll
    for (int ni = 0; ni < 4; ++ni)
      Oa[((size_t)(b * S_ + srow) * H_ + h) * DK_ + ni * 16 + l16] =
          f2bf(o[ni][r] * linv);
  }
}

// ---------------------------------------------------------------------------
// Final output GEMM: fp32 row-major C = A(bf16) @ Wo(bf16)^T  (unchanged)
// ---------------------------------------------------------------------------
__global__ __launch_bounds__(256)
void gemm_out(const unsigned short* __restrict__ A, const unsigned short* __restrict__ W,
              float* __restrict__ out) {
  __shared__ unsigned short As[2][128 * 32];
  __shared__ unsigned short Bs[2][128 * 32];
  const int lin = blockIdx.x + (blockIdx.y << 3);     // [0,256)
  const int v_  = (lin & 7) * 32 + (lin >> 3);        // bijective
  const int bx  = v_ & 7;
  const int by  = v_ >> 3;

  const int t = threadIdx.x, lane = t & 63, wave = t >> 6;
  const int l16 = lane & 15, quad = lane >> 4;
  const int wm = wave >> 1, wn = wave & 1;
  const int m0 = by * 128, j0 = bx * 128;

  f32x4 acc[4][4];
#pragma unroll
  for (int i = 0; i < 4; ++i)
#pragma unroll
    for (int j = 0; j < 4; ++j) acc[i][j] = (f32x4)(0.0f);

  auto stage = [&](int kb, int buf) {
#pragma unroll
    for (int i = 0; i < 2; ++i) {
      const int c  = (wave * 2 + i) * 64 + lane;
      const int r  = c >> 2;
      const int co = (c & 3) * 8;
      gl_lds16(&A[(size_t)(m0 + r) * D_ + kb + co], &As[buf][(wave * 2 + i) * 512]);
      gl_lds16(&W[(size_t)(j0 + r) * D_ + kb + co], &Bs[buf][(wave * 2 + i) * 512]);
    }
  };

  stage(0, 0);
  for (int kb = 0; kb < D_; kb += 32) {
    const int buf = (kb >> 5) & 1;
    __syncthreads();
    if (kb + 32 < D_) stage(kb + 32, buf ^ 1);

    bf16x8 af[4], bfr[4];
#pragma unroll
    for (int mi = 0; mi < 4; ++mi)
      af[mi] = *(const bf16x8*)&As[buf][(wm * 64 + mi * 16 + l16) * 32 + quad * 8];
#pragma unroll
    for (int ni = 0; ni < 4; ++ni)
      bfr[ni] = *(const bf16x8*)&Bs[buf][(wn * 64 + ni * 16 + l16) * 32 + quad * 8];
#pragma unroll
    for (int mi = 0; mi < 4; ++mi)
#pragma unroll
      for (int ni = 0; ni < 4; ++ni)
        acc[mi][ni] = MFMA_BF16(af[mi], bfr[ni], acc[mi][ni]);
  }

#pragma unroll
  for (int mi = 0; mi < 4; ++mi) {
    const int rowb = m0 + wm * 64 + mi * 16 + quad * 4;
#pragma unroll
    for (int ni = 0; ni < 4; ++ni) {
      const int col = j0 + wn * 64 + ni * 16 + l16;
#pragma unroll
      for (int r = 0; r < 4; ++r)
        out[(size_t)(rowb + r) * D_ + col] = acc[mi][ni][r];
    }
  }
}

// ---------------------------------------------------------------------------
extern "C" void kernel_launch(void* const* d_in, const int* in_sizes, int n_in,
                              void* d_out, int out_size, void* d_ws, size_t ws_size,
                              hipStream_t stream) {
  (void)in_sizes; (void)n_in; (void)out_size; (void)ws_size;
  const float* q  = (const float*)d_in[0];
  const float* k  = (const float*)d_in[1];
  const float* v  = (const float*)d_in[2];
  const float* Wq = (const float*)d_in[3];
  const float* Wk = (const float*)d_in[4];
  const float* Wv = (const float*)d_in[5];
  const float* Wo = (const float*)d_in[6];
  const float* qw = (const float*)d_in[7];
  const float* kw = (const float*)d_in[8];

  char* ws = (char*)d_ws;
  const size_t MB = 1u << 20;
  unsigned short* qb  = (unsigned short*)(ws + 0 * MB);    // bf16 inputs
  unsigned short* kb  = (unsigned short*)(ws + 8 * MB);
  unsigned short* vb  = (unsigned short*)(ws + 16 * MB);
  unsigned short* wqb = (unsigned short*)(ws + 24 * MB);
  unsigned short* wkb = (unsigned short*)(ws + 26 * MB);
  unsigned short* wvb = (unsigned short*)(ws + 28 * MB);
  unsigned short* wob = (unsigned short*)(ws + 30 * MB);
  unsigned short* Qb  = (unsigned short*)(ws + 32 * MB);   // normed+roped Q (scaled)
  unsigned short* Kb  = (unsigned short*)(ws + 40 * MB);   // normed+roped K
  unsigned short* Vtb = (unsigned short*)(ws + 48 * MB);   // V^T [bh][dk][s'] (sigma)
  unsigned short* Ab  = (unsigned short*)(ws + 56 * MB);   // attn out row-major

  cvt_bf16<<<dim3(4096, 7), 256, 0, stream>>>(q, k, v, Wq, Wk, Wv, Wo,
                                              qb, kb, vb, wqb, wkb, wvb, wob);

  gemm_qkv<<<dim3(4, 16, 3), 512, 0, stream>>>(
      qb, kb, vb, wqb, wkb, wvb, Qb, Kb, Vtb, qw, kw);

  flash3<<<1024, 256, 0, stream>>>(Qb, Kb, Vtb, Ab);

  gemm_out<<<dim3(D_ / 128, (B_ * S_) / 128), 256, 0, stream>>>(Ab, wob, (float*)d_out);
}

// Round 5
// 203.371 us; speedup vs baseline: 1.0346x; 1.0346x over previous
//
#include <hip/hip_runtime.h>
#include <hip/hip_bf16.h>
#include <math.h>

#define B_  2
#define S_  2048
#define D_  1024
#define H_  16
#define DK_ 64

typedef __attribute__((ext_vector_type(8))) short bf16x8;   // 8 bf16 = 4 VGPRs
typedef __attribute__((ext_vector_type(4))) float f32x4;
typedef __attribute__((ext_vector_type(4))) unsigned int u32x4;

#define MFMA_BF16(a, b, c) __builtin_amdgcn_mfma_f32_16x16x32_bf16((a), (b), (c), 0, 0, 0)

// 0.125 (1/sqrt(DK)) * log2(e): folded into Q so P = v_exp(S^T) directly
#define QSCALE 0.18033688011112042f
// log2(500000)/32 for RoPE inv_freq = 2^(-j * this)
#define ROPE_L2 0.591611512f

// fp32 -> bf16 round-to-nearest-even
__device__ __forceinline__ unsigned short f2bf(float f) {
  unsigned int u = __float_as_uint(f);
  u += 0x7FFFu + ((u >> 16) & 1u);
  return (unsigned short)(u >> 16);
}

// async global->LDS, 16 B per lane; LDS dest = wave-uniform base + lane*16
__device__ __forceinline__ void gl_lds16(const void* g, void* l) {
  __builtin_amdgcn_global_load_lds(
      (const __attribute__((address_space(1))) void*)g,
      (__attribute__((address_space(3))) void*)l, 16, 0, 0);
}

// XOR-swizzled LDS index (ushort units). Rows are 64 ushorts = 128 B = 8
// 16B-chunks; chunk ^= row&7 makes both gl_lds16 staging (identity per-lane
// slots) and column-slice fragment reads conflict-free.
__device__ __forceinline__ int lsw(int row, int col) {
  return row * 64 + ((((col) >> 3) ^ (row & 7)) << 3) + (col & 7);
}

// sigma-inverse for the V^T column permutation (6-bit in-tile s index).
// sigma pairs PV A-fragment slot s_r = ks*32 + quad*8 + j with the QK^T
// accumulator register (kvi = 2ks + (j>>2), r = j&3) of the SAME lane:
//   sigma(s_r) = kvi*16 + quad*4 + r  -> bit map y = (x5, x2, x4, x3, x1, x0)
// inverse:  x = (y5, y3, y2, y4, y1, y0).  Low 2 bits identity -> 4-wide
// uint2 stores in the V^T writer stay contiguous.
__device__ __forceinline__ int vperm_inv(int c) {   // c multiple of 4
  return (c & 32) | ((c & 8) << 1) | ((c & 4) << 1) | ((c & 16) >> 2);
}

// ---------------------------------------------------------------------------
// fp32 -> bf16 conversion for q,k,v and the four weight matrices.
// ---------------------------------------------------------------------------
__global__ __launch_bounds__(256)
void cvt_bf16(const float* __restrict__ q, const float* __restrict__ k,
              const float* __restrict__ v, const float* __restrict__ wq,
              const float* __restrict__ wk, const float* __restrict__ wv,
              const float* __restrict__ wo,
              unsigned short* __restrict__ qb, unsigned short* __restrict__ kb,
              unsigned short* __restrict__ vb, unsigned short* __restrict__ wqb,
              unsigned short* __restrict__ wkb, unsigned short* __restrict__ wvb,
              unsigned short* __restrict__ wob) {
  const float* src; unsigned short* dst; int n;
  switch (blockIdx.y) {
    case 0: src = q;  dst = qb;  n = B_ * S_ * D_; break;
    case 1: src = k;  dst = kb;  n = B_ * S_ * D_; break;
    case 2: src = v;  dst = vb;  n = B_ * S_ * D_; break;
    case 3: src = wq; dst = wqb; n = D_ * D_; break;
    case 4: src = wk; dst = wkb; n = D_ * D_; break;
    case 5: src = wv; dst = wvb; n = D_ * D_; break;
    default: src = wo; dst = wob; n = D_ * D_; break;
  }
  const int i = (blockIdx.x * 256 + threadIdx.x) * 4;
  if (i >= n) return;
  float4 val = *(const float4*)&src[i];
  ushort4 r4;
  r4.x = f2bf(val.x); r4.y = f2bf(val.y); r4.z = f2bf(val.z); r4.w = f2bf(val.w);
  *(ushort4*)&dst[i] = r4;
}

// ---------------------------------------------------------------------------
// Fused QKV projection GEMM (z selects q/k/v) with fused epilogues:
//   z=0: RMSNorm + RoPE + QSCALE -> bf16 head-major [b][h][s][dk]
//   z=1: RMSNorm + RoPE          -> bf16 head-major
//   z=2: plain                   -> bf16 V-TRANSPOSED [b][h][dk][s'],
//        s' = in-tile sigma-permuted (vperm_inv) so flash3's PV A-fragment
//        is a pure register pack of the QK^T accumulator (no P LDS trip).
// 128x128 tile, BK=32, double-buffered global_load_lds staging (m97 style).
// XCD-aware bijective swizzle (T1).  REVERTED to the verified round-3
// version: the 8-phase 256^2 port regressed here (grid 192 < 256 CUs,
// 1 block/CU at 128KB LDS, NT=16 -> schedule prerequisites unmet).
// ---------------------------------------------------------------------------
__global__ __launch_bounds__(256)
void gemm_qkv(const unsigned short* __restrict__ qa, const unsigned short* __restrict__ ka,
              const unsigned short* __restrict__ va,
              const unsigned short* __restrict__ wq, const unsigned short* __restrict__ wk,
              const unsigned short* __restrict__ wv,
              unsigned short* __restrict__ Qo, unsigned short* __restrict__ Ko,
              unsigned short* __restrict__ Vto,
              const float* __restrict__ qnw, const float* __restrict__ knw) {
  __shared__ unsigned short As[2][128 * 32];
  __shared__ unsigned short Bs[2][128 * 32];

  // XCD swizzle: lin in dispatch order (x fastest); XCD = lin % 8.
  const int lin = blockIdx.x + (blockIdx.y << 3) + (blockIdx.z << 8);  // [0,768)
  const int v_  = (lin & 7) * 96 + (lin >> 3);                          // bijective
  const int bx  = v_ & 7;            // j-tile within panel
  const int panel = v_ >> 3;         // [0,96)
  const int by  = panel & 31;        // m-tile
  const int z   = panel >> 5;        // q/k/v select

  const unsigned short* A = (z == 0) ? qa : (z == 1) ? ka : va;
  const unsigned short* W = (z == 0) ? wq : (z == 1) ? wk : wv;

  const int t = threadIdx.x, lane = t & 63, wave = t >> 6;
  const int l16 = lane & 15, quad = lane >> 4;
  const int wm = wave >> 1, wn = wave & 1;
  const int m0 = by * 128, j0 = bx * 128;

  f32x4 acc[4][4];
#pragma unroll
  for (int i = 0; i < 4; ++i)
#pragma unroll
    for (int j = 0; j < 4; ++j) acc[i][j] = (f32x4)(0.0f);

  auto stage = [&](int kb, int buf) {
#pragma unroll
    for (int i = 0; i < 2; ++i) {
      const int c  = (wave * 2 + i) * 64 + lane;  // 16B chunk id, 0..511
      const int r  = c >> 2;                      // tile row 0..127
      const int co = (c & 3) * 8;                 // ushort offset in 32-wide row
      gl_lds16(&A[(size_t)(m0 + r) * D_ + kb + co], &As[buf][(wave * 2 + i) * 512]);
      gl_lds16(&W[(size_t)(j0 + r) * D_ + kb + co], &Bs[buf][(wave * 2 + i) * 512]);
    }
  };

  stage(0, 0);
  for (int kb = 0; kb < D_; kb += 32) {
    const int buf = (kb >> 5) & 1;
    __syncthreads();                 // staged buf ready (vmcnt drained at barrier)
    if (kb + 32 < D_) stage(kb + 32, buf ^ 1);

    bf16x8 af[4], bfr[4];
#pragma unroll
    for (int mi = 0; mi < 4; ++mi)
      af[mi] = *(const bf16x8*)&As[buf][(wm * 64 + mi * 16 + l16) * 32 + quad * 8];
#pragma unroll
    for (int ni = 0; ni < 4; ++ni)
      bfr[ni] = *(const bf16x8*)&Bs[buf][(wn * 64 + ni * 16 + l16) * 32 + quad * 8];
#pragma unroll
    for (int mi = 0; mi < 4; ++mi)
#pragma unroll
      for (int ni = 0; ni < 4; ++ni)
        acc[mi][ni] = MFMA_BF16(af[mi], bfr[ni], acc[mi][ni]);
  }

  // epilogue. C/D layout: col = l16 (n), row = quad*4 + reg (m).
  const int h = bx * 2 + wn;   // one head per 64-col wave-half
  if (z == 2) {
    // V^T: [b][h][dk][s'], packed 4-bf16 (8B) stores along s (sigma cols)
#pragma unroll
    for (int mi = 0; mi < 4; ++mi) {
      const int rowb = m0 + wm * 64 + mi * 16 + quad * 4;
      const int b = rowb >> 11, s0 = rowb & (S_ - 1);
      const int sp = (s0 & ~63) | vperm_inv(s0 & 63);
#pragma unroll
      for (int ni = 0; ni < 4; ++ni) {
        const int dk = ni * 16 + l16;
        const unsigned int u0 =
            (unsigned int)f2bf(acc[mi][ni][0]) | ((unsigned int)f2bf(acc[mi][ni][1]) << 16);
        const unsigned int u1 =
            (unsigned int)f2bf(acc[mi][ni][2]) | ((unsigned int)f2bf(acc[mi][ni][3]) << 16);
        *(uint2*)&Vto[((size_t)((b * H_ + h) * DK_ + dk)) * S_ + sp] = make_uint2(u0, u1);
      }
    }
  } else {
    unsigned short* out = (z == 0) ? Qo : Ko;
    const float* nw = (z == 0) ? qnw : knw;
    const float sc  = (z == 0) ? QSCALE : 1.0f;
    float wv_[4];
#pragma unroll
    for (int ni = 0; ni < 4; ++ni) wv_[ni] = nw[ni * 16 + l16];
    const float invA = exp2f(-(float)l16 * ROPE_L2);         // j = l16
    const float invB = exp2f(-(float)(16 + l16) * ROPE_L2);  // j = 16 + l16
#pragma unroll
    for (int mi = 0; mi < 4; ++mi) {
#pragma unroll
      for (int r = 0; r < 4; ++r) {
        const int rowg = m0 + wm * 64 + mi * 16 + quad * 4 + r;
        const int b = rowg >> 11, s = rowg & (S_ - 1);
        float ss = 0.f;
#pragma unroll
        for (int ni = 0; ni < 4; ++ni) ss += acc[mi][ni][r] * acc[mi][ni][r];
#pragma unroll
        for (int m = 1; m < 16; m <<= 1) ss += __shfl_xor(ss, m);
        const float rms = rsqrtf(ss * (1.0f / DK_) + 1e-10f);
        float xn[4];
#pragma unroll
        for (int ni = 0; ni < 4; ++ni) xn[ni] = wv_[ni] * acc[mi][ni][r] * rms;
        const float fA = (float)s * invA, fB = (float)s * invB;
        const float cA = __cosf(fA) * sc, sA = __sinf(fA) * sc;
        const float cB = __cosf(fB) * sc, sB = __sinf(fB) * sc;
        float o0 = xn[0] * cA - xn[2] * sA;   // dk = l16       (<32, j=A)
        float o1 = xn[1] * cB - xn[3] * sB;   // dk = 16+l16    (<32, j=B)
        float o2 = xn[2] * cA + xn[0] * sA;   // dk = 32+l16    (>=32, j=A)
        float o3 = xn[3] * cB + xn[1] * sB;   // dk = 48+l16    (>=32, j=B)
        const size_t base = ((size_t)(b * H_ + h) * S_ + s) * DK_;
        out[base +  0 + l16] = f2bf(o0);
        out[base + 16 + l16] = f2bf(o1);
        out[base + 32 + l16] = f2bf(o2);
        out[base + 48 + l16] = f2bf(o3);
      }
    }
  }
}

// ---------------------------------------------------------------------------
// Flash attention v5: round-3 structure + T15 one-tile software pipeline.
// Per iteration: QK^T(kt) -> PV(kt-1) [independent: P(kt-1) in registers,
// V(kt-1) in its own LDS buffer] -> SM(kt).  The SM VALU (16 exp2 + packs)
// now overlaps PV's MFMA/ds_read instead of serializing the chain
// (T15: +7-11% measured on attn, m214v36).  V is TRIPLE-buffered (kt % 3):
// staging of V(kt+1) must not overwrite V(kt-1) still being read by the
// lagged PV.  K stays double-buffered (kt & 1).  LDS = 2*8 + 3*8 = 40 KB
// -> exactly 4 blocks/CU (160 KiB).  Two named P-states pwA/pwB, loop
// unrolled by 2 so all register arrays are statically indexed (rule #20).
// P never crosses lanes (sigma pairing; V columns pre-permuted by
// gemm_qkv's V^T writer).  s_setprio(1) wraps MFMA clusters (T5).
// ---------------------------------------------------------------------------
__global__ __launch_bounds__(256)
void flash3(const unsigned short* __restrict__ Q, const unsigned short* __restrict__ K,
            const unsigned short* __restrict__ Vt, unsigned short* __restrict__ Oa) {
  __shared__ unsigned short Ks[2][64 * 64];
  __shared__ unsigned short Vs[3][64 * 64];
  const int bx = blockIdx.x;
  const int idx = bx >> 5;
  const int qt = (idx < 16) ? idx : (47 - idx);   // balance across co-residents
  const int bh = bx & 31;
  const int t = threadIdx.x, lane = t & 63, wave = t >> 6;
  const int l16 = lane & 15, quad = lane >> 4;
  const size_t hb = (size_t)bh * S_ * DK_;
  const unsigned short* Qh  = Q + hb;
  const unsigned short* Kh  = K + hb;
  const unsigned short* Vth = Vt + hb;      // [dk][s'] (sigma-permuted cols)

  bf16x8 qf[2];
#pragma unroll
  for (int ks = 0; ks < 2; ++ks)
    qf[ks] = *(const bf16x8*)
      &Qh[(size_t)(qt * 64 + wave * 16 + l16) * DK_ + ks * 32 + quad * 8];

  bf16x8 ones;
#pragma unroll
  for (int j = 0; j < 8; ++j) ones[j] = (short)0x3F80;  // bf16 1.0

  f32x4 o[4], lacc;
  lacc = (f32x4)(0.0f);
#pragma unroll
  for (int ni = 0; ni < 4; ++ni) o[ni] = (f32x4)(0.0f);

  // stage 16 rows/wave of K tile (buf kb_) and V^T tile (buf vb_)
  auto stage = [&](int kt, int kb_, int vb_) {
#pragma unroll
    for (int i = 0; i < 2; ++i) {
      const int rbase = wave * 16 + i * 8;
      const int r = rbase + (lane >> 3);
      const int c = ((lane & 7) ^ (r & 7)) * 8;   // logical col (ushorts)
      gl_lds16(&Kh[(size_t)(kt * 64 + r) * DK_ + c], &Ks[kb_][rbase * 64]);
      gl_lds16(&Vth[(size_t)r * S_ + kt * 64 + c], &Vs[vb_][rbase * 64]);
    }
  };

  f32x4 sv[4];   // QK^T accumulator for the CURRENT tile (reused)

  // S^T = K Q^T : A = K-frag (m=kv), B = Q-frag (n=q)
  auto qkt = [&](int kt) {
    const int buf = kt & 1;
#pragma unroll
    for (int kvi = 0; kvi < 4; ++kvi) sv[kvi] = (f32x4)(0.0f);
#pragma unroll
    for (int ks = 0; ks < 2; ++ks) {
      bf16x8 ak[4];
#pragma unroll
      for (int kvi = 0; kvi < 4; ++kvi)
        ak[kvi] = *(const bf16x8*)&Ks[buf][lsw(kvi * 16 + l16, ks * 32 + quad * 8)];
      __builtin_amdgcn_s_setprio(1);
#pragma unroll
      for (int kvi = 0; kvi < 4; ++kvi)
        sv[kvi] = MFMA_BF16(ak[kvi], qf[ks], sv[kvi]);
      __builtin_amdgcn_s_setprio(0);
    }
  };

  // exp2 (+ mask on the single diagonal tile) -> packed bf16 P words
  auto smx = [&](int kt, unsigned int (&pw)[4][2]) {
    if (kt == qt) {
      const int qg = qt * 64 + wave * 16 + l16;
#pragma unroll
      for (int kvi = 0; kvi < 4; ++kvi) {
        float e[4];
#pragma unroll
        for (int r = 0; r < 4; ++r) {
          float x = sv[kvi][r];
          if ((kt * 64 + kvi * 16 + quad * 4 + r) > qg) x = -INFINITY;
          e[r] = exp2f(x);
        }
        pw[kvi][0] = (__float_as_uint(e[1]) & 0xFFFF0000u) | (__float_as_uint(e[0]) >> 16);
        pw[kvi][1] = (__float_as_uint(e[3]) & 0xFFFF0000u) | (__float_as_uint(e[2]) >> 16);
      }
    } else {
#pragma unroll
      for (int kvi = 0; kvi < 4; ++kvi) {
        float e[4];
#pragma unroll
        for (int r = 0; r < 4; ++r) e[r] = exp2f(sv[kvi][r]);
        pw[kvi][0] = (__float_as_uint(e[1]) & 0xFFFF0000u) | (__float_as_uint(e[0]) >> 16);
        pw[kvi][1] = (__float_as_uint(e[3]) & 0xFFFF0000u) | (__float_as_uint(e[2]) >> 16);
      }
    }
  };

  // O += P V, l += P 1  (A = P in regs via sigma pairing, B = Vs[vb_])
  auto pv = [&](const unsigned int (&pw)[4][2], int vb_) {
    bf16x8 ap[2];
#pragma unroll
    for (int ks = 0; ks < 2; ++ks) {
      u32x4 aw;
      aw.x = pw[2 * ks][0];
      aw.y = pw[2 * ks][1];
      aw.z = pw[2 * ks + 1][0];
      aw.w = pw[2 * ks + 1][1];
      ap[ks] = __builtin_bit_cast(bf16x8, aw);
    }
#pragma unroll
    for (int ks = 0; ks < 2; ++ks) {
      bf16x8 bv[4];
#pragma unroll
      for (int ni = 0; ni < 4; ++ni)
        bv[ni] = *(const bf16x8*)&Vs[vb_][lsw(ni * 16 + l16, ks * 32 + quad * 8)];
      __builtin_amdgcn_s_setprio(1);
#pragma unroll
      for (int ni = 0; ni < 4; ++ni)
        o[ni] = MFMA_BF16(ap[ks], bv[ni], o[ni]);
      lacc = MFMA_BF16(ap[ks], ones, lacc);
      __builtin_amdgcn_s_setprio(0);
    }
  };

  const int nkt = qt + 1;
  unsigned int pwA[4][2], pwB[4][2];

  // prologue: tile 0 (no lagged PV yet)
  stage(0, 0, 0);
  __syncthreads();
  if (nkt > 1) stage(1, 1, 1);
  qkt(0);
  smx(0, pwA);

  int kt = 1;
  for (; kt + 1 < nkt; kt += 2) {
    // even slot: current -> pwB, lagged PV consumes pwA
    __syncthreads();                       // stage(kt) done; V[(kt+1)%3] free
    stage(kt + 1, (kt + 1) & 1, (kt + 1) % 3);
    qkt(kt);
    pv(pwA, (kt - 1) % 3);
    smx(kt, pwB);
    // odd slot: current -> pwA, lagged PV consumes pwB
    __syncthreads();
    if (kt + 2 < nkt) stage(kt + 2, (kt + 2) & 1, (kt + 2) % 3);
    qkt(kt + 1);
    pv(pwB, kt % 3);
    smx(kt + 1, pwA);
  }
  if (kt < nkt) {          // one leftover tile (current -> pwB)
    __syncthreads();
    qkt(kt);
    pv(pwA, (kt - 1) % 3);
    smx(kt, pwB);
    pv(pwB, kt % 3);       // drain
  } else {                 // pairs consumed everything; drain pwA
    pv(pwA, (nkt - 1) % 3);
  }

  // epilogue: O /= l, write bf16 row-major attn [b*S+s][h*64+dk]
  const int b = bh >> 4, h = bh & 15;
#pragma unroll
  for (int r = 0; r < 4; ++r) {
    const int srow = qt * 64 + wave * 16 + quad * 4 + r;
    const float linv = 1.0f / lacc[r];
#pragma unroll
    for (int ni = 0; ni < 4; ++ni)
      Oa[((size_t)(b * S_ + srow) * H_ + h) * DK_ + ni * 16 + l16] =
          f2bf(o[ni][r] * linv);
  }
}

// ---------------------------------------------------------------------------
// Final output GEMM: fp32 row-major C = A(bf16) @ Wo(bf16)^T  (unchanged)
// XCD swizzle (T1): nwg = 256 = 8 * 32.
// ---------------------------------------------------------------------------
__global__ __launch_bounds__(256)
void gemm_out(const unsigned short* __restrict__ A, const unsigned short* __restrict__ W,
              float* __restrict__ out) {
  __shared__ unsigned short As[2][128 * 32];
  __shared__ unsigned short Bs[2][128 * 32];
  const int lin = blockIdx.x + (blockIdx.y << 3);     // [0,256)
  const int v_  = (lin & 7) * 32 + (lin >> 3);        // bijective
  const int bx  = v_ & 7;
  const int by  = v_ >> 3;

  const int t = threadIdx.x, lane = t & 63, wave = t >> 6;
  const int l16 = lane & 15, quad = lane >> 4;
  const int wm = wave >> 1, wn = wave & 1;
  const int m0 = by * 128, j0 = bx * 128;

  f32x4 acc[4][4];
#pragma unroll
  for (int i = 0; i < 4; ++i)
#pragma unroll
    for (int j = 0; j < 4; ++j) acc[i][j] = (f32x4)(0.0f);

  auto stage = [&](int kb, int buf) {
#pragma unroll
    for (int i = 0; i < 2; ++i) {
      const int c  = (wave * 2 + i) * 64 + lane;
      const int r  = c >> 2;
      const int co = (c & 3) * 8;
      gl_lds16(&A[(size_t)(m0 + r) * D_ + kb + co], &As[buf][(wave * 2 + i) * 512]);
      gl_lds16(&W[(size_t)(j0 + r) * D_ + kb + co], &Bs[buf][(wave * 2 + i) * 512]);
    }
  };

  stage(0, 0);
  for (int kb = 0; kb < D_; kb += 32) {
    const int buf = (kb >> 5) & 1;
    __syncthreads();
    if (kb + 32 < D_) stage(kb + 32, buf ^ 1);

    bf16x8 af[4], bfr[4];
#pragma unroll
    for (int mi = 0; mi < 4; ++mi)
      af[mi] = *(const bf16x8*)&As[buf][(wm * 64 + mi * 16 + l16) * 32 + quad * 8];
#pragma unroll
    for (int ni = 0; ni < 4; ++ni)
      bfr[ni] = *(const bf16x8*)&Bs[buf][(wn * 64 + ni * 16 + l16) * 32 + quad * 8];
#pragma unroll
    for (int mi = 0; mi < 4; ++mi)
#pragma unroll
      for (int ni = 0; ni < 4; ++ni)
        acc[mi][ni] = MFMA_BF16(af[mi], bfr[ni], acc[mi][ni]);
  }

#pragma unroll
  for (int mi = 0; mi < 4; ++mi) {
    const int rowb = m0 + wm * 64 + mi * 16 + quad * 4;
#pragma unroll
    for (int ni = 0; ni < 4; ++ni) {
      const int col = j0 + wn * 64 + ni * 16 + l16;
#pragma unroll
      for (int r = 0; r < 4; ++r)
        out[(size_t)(rowb + r) * D_ + col] = acc[mi][ni][r];
    }
  }
}

// ---------------------------------------------------------------------------
extern "C" void kernel_launch(void* const* d_in, const int* in_sizes, int n_in,
                              void* d_out, int out_size, void* d_ws, size_t ws_size,
                              hipStream_t stream) {
  (void)in_sizes; (void)n_in; (void)out_size; (void)ws_size;
  const float* q  = (const float*)d_in[0];
  const float* k  = (const float*)d_in[1];
  const float* v  = (const float*)d_in[2];
  const float* Wq = (const float*)d_in[3];
  const float* Wk = (const float*)d_in[4];
  const float* Wv = (const float*)d_in[5];
  const float* Wo = (const float*)d_in[6];
  const float* qw = (const float*)d_in[7];
  const float* kw = (const float*)d_in[8];

  char* ws = (char*)d_ws;
  const size_t MB = 1u << 20;
  unsigned short* qb  = (unsigned short*)(ws + 0 * MB);    // bf16 inputs
  unsigned short* kb  = (unsigned short*)(ws + 8 * MB);
  unsigned short* vb  = (unsigned short*)(ws + 16 * MB);
  unsigned short* wqb = (unsigned short*)(ws + 24 * MB);
  unsigned short* wkb = (unsigned short*)(ws + 26 * MB);
  unsigned short* wvb = (unsigned short*)(ws + 28 * MB);
  unsigned short* wob = (unsigned short*)(ws + 30 * MB);
  unsigned short* Qb  = (unsigned short*)(ws + 32 * MB);   // normed+roped Q (scaled)
  unsigned short* Kb  = (unsigned short*)(ws + 40 * MB);   // normed+roped K
  unsigned short* Vtb = (unsigned short*)(ws + 48 * MB);   // V^T [bh][dk][s'] (sigma)
  unsigned short* Ab  = (unsigned short*)(ws + 56 * MB);   // attn out row-major

  cvt_bf16<<<dim3(4096, 7), 256, 0, stream>>>(q, k, v, Wq, Wk, Wv, Wo,
                                              qb, kb, vb, wqb, wkb, wvb, wob);

  gemm_qkv<<<dim3(D_ / 128, (B_ * S_) / 128, 3), 256, 0, stream>>>(
      qb, kb, vb, wqb, wkb, wvb, Qb, Kb, Vtb, qw, kw);

  flash3<<<1024, 256, 0, stream>>>(Qb, Kb, Vtb, Ab);

  gemm_out<<<dim3(D_ / 128, (B_ * S_) / 128), 256, 0, stream>>>(Ab, wob, (float*)d_out);
}